// Round 1
// baseline (3178.992 us; speedup 1.0000x reference)
//
#include <hip/hip_runtime.h>

// SOM best-matching-unit one-hot:
//   d2[n,k] = ||x_n||^2 + ||w_k||^2 - 2 x_n . w_k ; bmu = argmin_k ; out = one_hot
// ||x_n||^2 is constant per row -> argmin over s_k = ||w_k||^2 - 2 x_n . w_k.
//
// Round 1: correctness-first. fp64 accumulation (fp32*fp32 products are exact
// in fp64) so our argmin == true argmin; avoids one-hot flips on near-ties
// (top-2 gap ~ Exp(mean 7); fp32 noise ~1e-4 -> ~1.4 expected flips over 100k
// samples, i.e. coin-flip failure -- fp64 makes it ~0).

#define SOM_K 1024
#define SOM_D 128
#define BLOCK 64   // 1 wave per block -> ~6 blocks/CU at N=100000, good balance

__global__ __launch_bounds__(BLOCK, 2) void som_bmu_kernel(
    const float* __restrict__ x,
    const float* __restrict__ w,
    float* __restrict__ out,
    int n_samples)
{
    __shared__ double wsq[SOM_K];  // 8 KB

    const int t = threadIdx.x;

    // Cooperative ||w_k||^2 in fp64 (redundant per block; ~0.4% of main work).
    for (int k = t; k < SOM_K; k += BLOCK) {
        const float* wk = w + k * SOM_D;
        double s = 0.0;
        #pragma unroll 16
        for (int d = 0; d < SOM_D; ++d) {
            double wd = (double)wk[d];
            s += wd * wd;
        }
        wsq[k] = s;
    }

    const int n = blockIdx.x * BLOCK + t;
    const int n_cl = (n < n_samples) ? n : (n_samples - 1);

    // x row -> 128 fp32 VGPRs via float4 loads.
    float xr[SOM_D];
    const float4* xp = (const float4*)(x + (size_t)n_cl * SOM_D);
    #pragma unroll
    for (int i = 0; i < SOM_D / 4; ++i) {
        float4 v = xp[i];
        xr[4 * i + 0] = v.x;
        xr[4 * i + 1] = v.y;
        xr[4 * i + 2] = v.z;
        xr[4 * i + 3] = v.w;
    }

    __syncthreads();

    double best = 1.0e300;
    int bestk = 0;

    // k-loop: w accesses are thread-uniform -> scalar loads (K$/L2-resident).
    #pragma unroll 1
    for (int k = 0; k < SOM_K; ++k) {
        const float* wk = w + k * SOM_D;
        double d0 = 0.0, d1 = 0.0, d2 = 0.0, d3 = 0.0;  // 4 chains for ILP
        #pragma unroll
        for (int d = 0; d < SOM_D; d += 4) {
            d0 += (double)xr[d + 0] * (double)wk[d + 0];
            d1 += (double)xr[d + 1] * (double)wk[d + 1];
            d2 += (double)xr[d + 2] * (double)wk[d + 2];
            d3 += (double)xr[d + 3] * (double)wk[d + 3];
        }
        double s = wsq[k] - 2.0 * ((d0 + d1) + (d2 + d3));
        if (s < best) { best = s; bestk = k; }  // strict < == first-min (np.argmin)
    }

    if (n < n_samples) {
        out[(size_t)n * SOM_K + bestk] = 1.0f;
    }
}

extern "C" void kernel_launch(void* const* d_in, const int* in_sizes, int n_in,
                              void* d_out, int out_size, void* d_ws, size_t ws_size,
                              hipStream_t stream) {
    const float* x = (const float*)d_in[0];
    const float* w = (const float*)d_in[1];
    float* out = (float*)d_out;

    const int n_samples = in_sizes[0] / SOM_D;  // 100000

    // d_out is re-poisoned to 0xAA before every timed launch -> zero it here.
    hipMemsetAsync(d_out, 0, (size_t)out_size * sizeof(float), stream);

    const int grid = (n_samples + BLOCK - 1) / BLOCK;
    som_bmu_kernel<<<grid, BLOCK, 0, stream>>>(x, w, out, n_samples);
}